// Round 13
// baseline (171.837 us; speedup 1.0000x reference)
//
#include <hip/hip_runtime.h>

#define DIMSZ 2048
#define NH 32
#define NKV 8
#define HD 64
#define SEQLEN 2048
#define BATCH 2
#define NROWS (BATCH*SEQLEN)   // 4096
#define NQKVC 3072             // 2048 q + 512 k + 512 v

typedef __bf16 bf16x8 __attribute__((ext_vector_type(8)));
typedef __bf16 bf16x2 __attribute__((ext_vector_type(2)));
typedef float f32x4v __attribute__((ext_vector_type(4)));
typedef float f32x2v __attribute__((ext_vector_type(2)));
typedef float f32x16 __attribute__((ext_vector_type(16)));

__device__ __forceinline__ unsigned short f2bf(float f) {
  __bf16 h = (__bf16)f;
  union { __bf16 h; unsigned short u; } v; v.h = h; return v.u;
}
__device__ __forceinline__ unsigned int pk2bf(float lo, float hi) {
  f32x2v v; v[0] = lo; v[1] = hi;
  bf16x2 h = __builtin_convertvector(v, bf16x2);
  union { bf16x2 h; unsigned int u; } c; c.h = h; return c.u;
}
// XOR swizzle for LDS tiles with 128-byte rows.
__device__ __forceinline__ int swz128(int row, int colBytes) {
  return row * 128 + (colBytes ^ ((row & 7) << 4));
}

#define GLOAD16(g, l) __builtin_amdgcn_global_load_lds( \
    (const __attribute__((address_space(1))) unsigned int*)(g), \
    (__attribute__((address_space(3))) unsigned int*)(l), 16, 0, 0)

// ---------------- merged fp32 -> bf16 convert (x | wq|wk|wv | wo) ----------------
__global__ void k_cvt_all(const float* __restrict__ x,
                          const float* __restrict__ wq, const float* __restrict__ wk,
                          const float* __restrict__ wv, const float* __restrict__ wo,
                          unsigned short* __restrict__ xb,
                          unsigned short* __restrict__ wqkvb,
                          unsigned short* __restrict__ wob) {
  int i = blockIdx.x * 256 + threadIdx.x;   // 4,718,592 float4 total
  const float* s; unsigned short* d; int soff, doff;
  if (i < 2097152)        { s = x;  d = xb;    soff = i;           doff = i; }
  else if (i < 3145728)   { s = wq; d = wqkvb; soff = i - 2097152; doff = i - 2097152; }
  else if (i < 3407872)   { s = wk; d = wqkvb; soff = i - 3145728; doff = i - 2097152; }
  else if (i < 3670016)   { s = wv; d = wqkvb; soff = i - 3407872; doff = i - 2097152; }
  else                    { s = wo; d = wob;   soff = i - 3670016; doff = i - 3670016; }
  float4 v = reinterpret_cast<const float4*>(s)[soff];
  uint2 pk; pk.x = pk2bf(v.x, v.y); pk.y = pk2bf(v.z, v.w);
  reinterpret_cast<uint2*>(d)[doff] = pk;
}

// ---------------- QKV GEMM with fused RoPE / V-transpose epilogue ----------------
__global__ __launch_bounds__(256, 2) void k_gemm_qkv(
    const unsigned short* __restrict__ A,
    const unsigned short* __restrict__ B,
    const float* __restrict__ fc, const float* __restrict__ fs,
    unsigned short* __restrict__ Qb, unsigned short* __restrict__ Kb,
    unsigned short* __restrict__ Vt)
{
  constexpr int BK = 64, K = DIMSZ;
  __shared__ __attribute__((aligned(16))) unsigned short smA[128 * BK];
  __shared__ __attribute__((aligned(16))) unsigned short smB[128 * BK];
  const int tid = threadIdx.x;
  const int lane = tid & 63;
  const int wid = tid >> 6;
  const int lr = lane & 15, lg = lane >> 4;
  const int gx = gridDim.x;
  int lin = blockIdx.y * gx + blockIdx.x;
  const int cpx = (gx * gridDim.y) >> 3;
  lin = (lin & 7) * cpx + (lin >> 3);
  const int m0 = (lin / gx) * 128, n0 = (lin % gx) * 128;
  const int wr = (wid >> 1) * 64, wc = (wid & 1) * 64;

  f32x4v acc[4][4];
  #pragma unroll
  for (int i = 0; i < 4; i++)
    #pragma unroll
    for (int j = 0; j < 4; j++)
      acc[i][j] = f32x4v{0.f, 0.f, 0.f, 0.f};

  for (int k0 = 0; k0 < K; k0 += BK) {
    #pragma unroll
    for (int c = 0; c < 4; c++) {
      const int chunk = wid * 4 + c;
      const int idx = chunk * 64 + lane;
      const int row = idx >> 3, s = idx & 7;
      const int ks = (s ^ (row & 7)) * 8;
      GLOAD16(A + (size_t)(m0 + row) * K + k0 + ks, &smA[chunk * 512]);
      GLOAD16(B + (size_t)(n0 + row) * K + k0 + ks, &smB[chunk * 512]);
    }
    __syncthreads();
    #pragma unroll
    for (int ks = 0; ks < 2; ks++) {
      bf16x8 af[4], bfv[4];
      #pragma unroll
      for (int m = 0; m < 4; m++)
        af[m] = *reinterpret_cast<const bf16x8*>((char*)smA + swz128(wr + m * 16 + lr, ks * 64 + lg * 16));
      #pragma unroll
      for (int n = 0; n < 4; n++)
        bfv[n] = *reinterpret_cast<const bf16x8*>((char*)smB + swz128(wc + n * 16 + lr, ks * 64 + lg * 16));
      #pragma unroll
      for (int m = 0; m < 4; m++)
        #pragma unroll
        for (int n = 0; n < 4; n++)
          acc[m][n] = __builtin_amdgcn_mfma_f32_16x16x32_bf16(af[m], bfv[n], acc[m][n], 0, 0, 0);
    }
    __syncthreads();
  }
  const int bx = n0 >> 7;
  if (bx < 20) {
    const bool isQ = bx < 16;
    const float SCL = isQ ? 0.18033688011112043f : 1.0f;   // 0.125*log2(e) for Q
    #pragma unroll
    for (int n = 0; n < 4; n++) {
      const int col = n0 + wc + n * 16 + lr;
      const int d = col & 63;
      const int i = d >> 1;
      const float sgn = (d & 1) ? 1.0f : -1.0f;
      unsigned short* dst;
      if (isQ) dst = Qb + (size_t)(col >> 6) * (SEQLEN * HD) + d;
      else     dst = Kb + (size_t)((col - 2048) >> 6) * (SEQLEN * HD) + d;
      #pragma unroll
      for (int m = 0; m < 4; m++)
        #pragma unroll
        for (int r = 0; r < 4; r++) {
          const int row = m0 + wr + m * 16 + lg * 4 + r;
          const int s = row & (SEQLEN - 1), b = row >> 11;
          const float v = acc[m][n][r];
          const float p = __shfl_xor(v, 1);
          const float c = fc[s * 32 + i], sn = fs[s * 32 + i];
          const float o = (v * c + sgn * p * sn) * SCL;
          const size_t headStride = (size_t)(isQ ? NH : NKV) * SEQLEN * HD;
          dst[(size_t)b * headStride + (size_t)s * HD] = f2bf(o);
        }
    }
  } else {
    #pragma unroll
    for (int n = 0; n < 4; n++) {
      const int col = n0 + wc + n * 16 + lr;
      const int kvh = (col - 2560) >> 6, d = col & 63;
      #pragma unroll
      for (int m = 0; m < 4; m++) {
        const int row0 = m0 + wr + m * 16 + lg * 4;
        const int s0 = row0 & (SEQLEN - 1), b = row0 >> 11;
        uint2 pk;
        pk.x = pk2bf(acc[m][n][0], acc[m][n][1]);
        pk.y = pk2bf(acc[m][n][2], acc[m][n][3]);
        *reinterpret_cast<uint2*>(
            Vt + ((size_t)((b * NKV + kvh) * HD) + d) * SEQLEN + s0) = pk;
      }
    }
  }
}

// ---------------- GEMM: C[M][N] = A[M][K] * B[N][K]^T (O-projection) ----------------
template<int OUT_BF16>
__global__ __launch_bounds__(256, 2) void k_gemm_bt(
    const unsigned short* __restrict__ A,
    const unsigned short* __restrict__ B,
    void* __restrict__ Cv, int M, int N, int K)
{
  constexpr int BK = 64;
  __shared__ __attribute__((aligned(16))) unsigned short smA[128 * BK];
  __shared__ __attribute__((aligned(16))) unsigned short smB[128 * BK];
  const int tid = threadIdx.x;
  const int lane = tid & 63;
  const int wid = tid >> 6;
  const int lr = lane & 15, lg = lane >> 4;
  const int gx = gridDim.x;
  int lin = blockIdx.y * gx + blockIdx.x;
  const int cpx = (gx * gridDim.y) >> 3;
  lin = (lin & 7) * cpx + (lin >> 3);
  const int m0 = (lin / gx) * 128, n0 = (lin % gx) * 128;
  const int wr = (wid >> 1) * 64, wc = (wid & 1) * 64;

  f32x4v acc[4][4];
  #pragma unroll
  for (int i = 0; i < 4; i++)
    #pragma unroll
    for (int j = 0; j < 4; j++)
      acc[i][j] = f32x4v{0.f, 0.f, 0.f, 0.f};

  for (int k0 = 0; k0 < K; k0 += BK) {
    #pragma unroll
    for (int c = 0; c < 4; c++) {
      const int chunk = wid * 4 + c;
      const int idx = chunk * 64 + lane;
      const int row = idx >> 3, s = idx & 7;
      const int ks = (s ^ (row & 7)) * 8;
      GLOAD16(A + (size_t)(m0 + row) * K + k0 + ks, &smA[chunk * 512]);
      GLOAD16(B + (size_t)(n0 + row) * K + k0 + ks, &smB[chunk * 512]);
    }
    __syncthreads();
    #pragma unroll
    for (int ks = 0; ks < 2; ks++) {
      bf16x8 af[4], bfv[4];
      #pragma unroll
      for (int m = 0; m < 4; m++)
        af[m] = *reinterpret_cast<const bf16x8*>((char*)smA + swz128(wr + m * 16 + lr, ks * 64 + lg * 16));
      #pragma unroll
      for (int n = 0; n < 4; n++)
        bfv[n] = *reinterpret_cast<const bf16x8*>((char*)smB + swz128(wc + n * 16 + lr, ks * 64 + lg * 16));
      #pragma unroll
      for (int m = 0; m < 4; m++)
        #pragma unroll
        for (int n = 0; n < 4; n++)
          acc[m][n] = __builtin_amdgcn_mfma_f32_16x16x32_bf16(af[m], bfv[n], acc[m][n], 0, 0, 0);
    }
    __syncthreads();
  }
  #pragma unroll
  for (int m = 0; m < 4; m++)
    #pragma unroll
    for (int n = 0; n < 4; n++)
      #pragma unroll
      for (int r = 0; r < 4; r++) {
        const size_t row = m0 + wr + m * 16 + lg * 4 + r;
        const size_t col = n0 + wc + n * 16 + lr;
        if (OUT_BF16) ((unsigned short*)Cv)[row * N + col] = f2bf(acc[m][n][r]);
        else          ((float*)Cv)[row * N + col] = acc[m][n][r];
      }
}

// ---------------- flash attention: 32x32 MFMA, merged-pair softmax ----------------
// Round 13: widen the per-barrier window — each interval computes TWO 64-kv
// tiles with ONE merged softmax over 128 kv: 2 independent QK MFMA chains
// (2-way MFMA ILP), 64 independent exp2, 1 tree/defer/rescale, HALF the
// barriers (nt/2+1). 8 static LDS buffers (64KB, 2 blocks/CU). Compute math
// per sub-tile identical to verified round-8 code.
__global__ __launch_bounds__(256, 2) void k_attn(
    const unsigned short* __restrict__ Qg,   // [B][NH][S][HD], scaled 0.125*log2e
    const unsigned short* __restrict__ Kg,   // [B][NKV][S][HD]
    const unsigned short* __restrict__ Vt,   // [B][NKV][HD][S]
    unsigned short* __restrict__ Og)         // [B*S][NH*HD]
{
  constexpr int KVB = 64;
  __shared__ __attribute__((aligned(16))) unsigned short sK0[KVB * HD];
  __shared__ __attribute__((aligned(16))) unsigned short sK1[KVB * HD];
  __shared__ __attribute__((aligned(16))) unsigned short sK2[KVB * HD];
  __shared__ __attribute__((aligned(16))) unsigned short sK3[KVB * HD];
  __shared__ __attribute__((aligned(16))) unsigned short sV0[HD * KVB];
  __shared__ __attribute__((aligned(16))) unsigned short sV1[HD * KVB];
  __shared__ __attribute__((aligned(16))) unsigned short sV2[HD * KVB];
  __shared__ __attribute__((aligned(16))) unsigned short sV3[HD * KVB];
  const int tid = threadIdx.x;
  const int lane = tid & 63, wid = tid >> 6;       // 4 waves
  const int l31 = lane & 31, hi = lane >> 5;
  // XCD swizzle: each XCD owns one kv-head panel (round-8 mapping)
  const int orig = blockIdx.x;                     // 512 blocks
  const int w = (orig & 7) * 64 + (orig >> 3);
  const int kvh = w >> 6;
  const int b = (w >> 5) & 1;
  const int h = kvh * 4 + ((w >> 3) & 3);
  const int qp = w & 7;
  const unsigned short* Qp = Qg + ((size_t)(b * NH + h) * SEQLEN) * HD;
  const unsigned short* Kp = Kg + ((size_t)(b * NKV + kvh) * SEQLEN) * HD;
  const unsigned short* Vp = Vt + ((size_t)(b * NKV + kvh) * HD) * SEQLEN;

  // staging: 8 chunks of 1KB per 8KB tile; wave wid owns chunks 2wid, 2wid+1
  int srow[2], scol[2];
  #pragma unroll
  for (int cc = 0; cc < 2; cc++) {
    const int idx = (wid * 2 + cc) * 64 + lane;
    srow[cc] = idx >> 3;
    scol[cc] = ((idx & 7) ^ (srow[cc] & 7)) * 8;
  }

  for (int phase = 0; phase < 2; phase++) {
    const int qt = phase ? (15 - qp) : qp;
    const int qrow0 = qt * 128 + wid * 32;
    const int qg = qrow0 + l31;
    bf16x8 aq[4];
    #pragma unroll
    for (int ks = 0; ks < 4; ks++)
      aq[ks] = *reinterpret_cast<const bf16x8*>(Qp + (size_t)qg * HD + ks * 16 + hi * 8);

    f32x16 accO0, accO1;
    #pragma unroll
    for (int ii = 0; ii < 16; ii++) { accO0[ii] = 0.f; accO1[ii] = 0.f; }
    float mrun = -3.0e38f, lrun = 0.f;

    auto STAGE_K = [&](int t, unsigned short* buf) {
      #pragma unroll
      for (int cc = 0; cc < 2; cc++)
        GLOAD16(Kp + (size_t)(t * KVB + srow[cc]) * HD + scol[cc], &buf[(wid * 2 + cc) * 512]);
    };
    auto STAGE_V = [&](int t, unsigned short* buf) {
      #pragma unroll
      for (int cc = 0; cc < 2; cc++)
        GLOAD16(Vp + (size_t)srow[cc] * SEQLEN + t * KVB + scol[cc], &buf[(wid * 2 + cc) * 512]);
    };

    // one merged pass over 128 kv = sub-tiles A [kv0,kv0+64) and B [+64,+128)
    auto PAIR = [&](int kv0, const unsigned short* bKa, const unsigned short* bKb,
                    const unsigned short* bVa, const unsigned short* bVb) {
      if (kv0 > qrow0 + 31) return;        // whole pair masked for this wave
      f32x16 SA0, SA1, SB0, SB1;
      #pragma unroll
      for (int ii = 0; ii < 16; ii++) { SA0[ii] = 0.f; SA1[ii] = 0.f; SB0[ii] = 0.f; SB1[ii] = 0.f; }
      __builtin_amdgcn_s_setprio(1);
      #pragma unroll
      for (int ks = 0; ks < 4; ks++) {
        bf16x8 a0 = *reinterpret_cast<const bf16x8*>((const char*)bKa + swz128(l31,      ks * 32 + hi * 16));
        bf16x8 a1 = *reinterpret_cast<const bf16x8*>((const char*)bKa + swz128(32 + l31, ks * 32 + hi * 16));
        bf16x8 b0 = *reinterpret_cast<const bf16x8*>((const char*)bKb + swz128(l31,      ks * 32 + hi * 16));
        bf16x8 b1 = *reinterpret_cast<const bf16x8*>((const char*)bKb + swz128(32 + l31, ks * 32 + hi * 16));
        SA0 = __builtin_amdgcn_mfma_f32_32x32x16_bf16(a0, aq[ks], SA0, 0, 0, 0);
        SA1 = __builtin_amdgcn_mfma_f32_32x32x16_bf16(a1, aq[ks], SA1, 0, 0, 0);
        SB0 = __builtin_amdgcn_mfma_f32_32x32x16_bf16(b0, aq[ks], SB0, 0, 0, 0);
        SB1 = __builtin_amdgcn_mfma_f32_32x32x16_bf16(b1, aq[ks], SB1, 0, 0, 0);
      }
      __builtin_amdgcn_s_setprio(0);
      if (kv0 + 2 * KVB - 1 > qrow0) {     // pair touches the diagonal
        #pragma unroll
        for (int reg = 0; reg < 16; reg++) {
          const int rl = (reg & 3) + 8 * (reg >> 2) + (hi << 2);
          if (kv0 + rl > qg)      SA0[reg] = -1.0e30f;
          if (kv0 + 32 + rl > qg) SA1[reg] = -1.0e30f;
          if (kv0 + 64 + rl > qg) SB0[reg] = -1.0e30f;
          if (kv0 + 96 + rl > qg) SB1[reg] = -1.0e30f;
        }
      }
      // merged row max over 64 regs + 1 cross-half exchange
      float t16[16];
      #pragma unroll
      for (int ii = 0; ii < 16; ii++)
        t16[ii] = fmaxf(fmaxf(SA0[ii], SA1[ii]), fmaxf(SB0[ii], SB1[ii]));
      float t8[8];
      #pragma unroll
      for (int ii = 0; ii < 8; ii++) t8[ii] = fmaxf(t16[ii], t16[ii + 8]);
      float t4[4];
      #pragma unroll
      for (int ii = 0; ii < 4; ii++) t4[ii] = fmaxf(t8[ii], t8[ii + 4]);
      float tm = fmaxf(fmaxf(t4[0], t4[1]), fmaxf(t4[2], t4[3]));
      tm = fmaxf(tm, __shfl_xor(tm, 32));
      const float mo = mrun;
      const bool defer = __all(tm <= mo + 8.0f);   // T13, log2 domain
      const float mn = defer ? mo : fmaxf(mo, tm);
      #pragma unroll
      for (int ii = 0; ii < 16; ii++) {
        SA0[ii] = __builtin_amdgcn_exp2f(SA0[ii] - mn);
        SA1[ii] = __builtin_amdgcn_exp2f(SA1[ii] - mn);
        SB0[ii] = __builtin_amdgcn_exp2f(SB0[ii] - mn);
        SB1[ii] = __builtin_amdgcn_exp2f(SB1[ii] - mn);
      }
      float u16[16];
      #pragma unroll
      for (int ii = 0; ii < 16; ii++)
        u16[ii] = (SA0[ii] + SA1[ii]) + (SB0[ii] + SB1[ii]);
      float u8[8];
      #pragma unroll
      for (int ii = 0; ii < 8; ii++) u8[ii] = u16[ii] + u16[ii + 8];
      float u4[4];
      #pragma unroll
      for (int ii = 0; ii < 4; ii++) u4[ii] = u8[ii] + u8[ii + 4];
      float rs = (u4[0] + u4[1]) + (u4[2] + u4[3]);
      rs += __shfl_xor(rs, 32);
      if (defer) {
        lrun += rs;
      } else {
        const float sc = __builtin_amdgcn_exp2f(mo - mn);
        mrun = mn;
        lrun = lrun * sc + rs;
        #pragma unroll
        for (int reg = 0; reg < 16; reg++) {
          const int rl = (reg & 3) + 8 * (reg >> 2) + (hi << 2);
          const float scr = __shfl(sc, rl);
          accO0[reg] *= scr; accO1[reg] *= scr;
        }
      }
      // PV for both sub-tiles (A-frags built in-register, T12)
      __builtin_amdgcn_s_setprio(1);
      #define PVSTEP(S16, G, BV, CB) do {                                      \
        unsigned a0 = pk2bf(S16[(G)+0], S16[(G)+1]);                           \
        unsigned a1 = pk2bf(S16[(G)+2], S16[(G)+3]);                           \
        unsigned b0 = pk2bf(S16[(G)+4], S16[(G)+5]);                           \
        unsigned b1 = pk2bf(S16[(G)+6], S16[(G)+7]);                           \
        unsigned s0 = hi ? a0 : b0, s1 = hi ? a1 : b1;                         \
        unsigned r0 = __shfl_xor((int)s0, 32), r1 = __shfl_xor((int)s1, 32);   \
        union { unsigned u[4]; bf16x8 v; } pf;                                 \
        pf.u[0] = hi ? r0 : a0; pf.u[1] = hi ? r1 : a1;                        \
        pf.u[2] = hi ? b0 : r0; pf.u[3] = hi ? b1 : r1;                        \
        bf16x8 bv0 = *reinterpret_cast<const bf16x8*>((const char*)(BV) + swz128(l31,      (CB))); \
        bf16x8 bv1 = *reinterpret_cast<const bf16x8*>((const char*)(BV) + swz128(32 + l31, (CB))); \
        accO0 = __builtin_amdgcn_mfma_f32_32x32x16_bf16(pf.v, bv0, accO0, 0, 0, 0); \
        accO1 = __builtin_amdgcn_mfma_f32_32x32x16_bf16(pf.v, bv1, accO1, 0, 0, 0); \
      } while (0)
      PVSTEP(SA0, 0, bVa,  0  + hi * 16);
      PVSTEP(SA0, 8, bVa,  32 + hi * 16);
      PVSTEP(SA1, 0, bVa,  64 + hi * 16);
      PVSTEP(SA1, 8, bVa,  96 + hi * 16);
      PVSTEP(SB0, 0, bVb,  0  + hi * 16);
      PVSTEP(SB0, 8, bVb,  32 + hi * 16);
      PVSTEP(SB1, 0, bVb,  64 + hi * 16);
      PVSTEP(SB1, 8, bVb,  96 + hi * 16);
      #undef PVSTEP
      __builtin_amdgcn_s_setprio(0);
    };

    const int nt = qt * 2 + 2;    // even; pairs = nt/2
    // prologue: pair 0 (tiles 0,1) into buffer set A
    STAGE_K(0, sK0); STAGE_K(1, sK1);
    STAGE_V(0, sV0); STAGE_V(1, sV1);
    __syncthreads();
    for (int t = 0; t < nt; t += 4) {
      // interval 1: compute pair(t) in set A; prefetch pair(t+2) into set B
      if (t + 2 < nt) { STAGE_K(t + 2, sK2); STAGE_K(t + 3, sK3);
                        STAGE_V(t + 2, sV2); STAGE_V(t + 3, sV3); }
      PAIR(t * KVB, sK0, sK1, sV0, sV1);
      __syncthreads();
      // interval 2: compute pair(t+2) in set B; prefetch pair(t+4) into set A
      if (t + 2 < nt) {
        if (t + 4 < nt) { STAGE_K(t + 4, sK0); STAGE_K(t + 5, sK1);
                          STAGE_V(t + 4, sV0); STAGE_V(t + 5, sV1); }
        PAIR((t + 2) * KVB, sK2, sK3, sV2, sV3);
        __syncthreads();
      }
    }
    // normalize + store
    const float inv = 1.0f / lrun;
    #pragma unroll
    for (int reg = 0; reg < 16; reg++) {
      const int rl = (reg & 3) + 8 * (reg >> 2) + (hi << 2);
      const float invr = __shfl(inv, rl);
      const int q = qrow0 + rl;
      const size_t base = ((size_t)(b * SEQLEN + q)) * DIMSZ + h * HD;
      Og[base + l31]      = f2bf(accO0[reg] * invr);
      Og[base + 32 + l31] = f2bf(accO1[reg] * invr);
    }
  }
}

extern "C" void kernel_launch(void* const* d_in, const int* in_sizes, int n_in,
                              void* d_out, int out_size, void* d_ws, size_t ws_size,
                              hipStream_t stream)
{
  const float* x  = (const float*)d_in[0];
  const float* fc = (const float*)d_in[1];
  const float* fs = (const float*)d_in[2];
  const float* wq = (const float*)d_in[3];
  const float* wk = (const float*)d_in[4];
  const float* wv = (const float*)d_in[5];
  const float* wo = (const float*)d_in[6];
  float* out = (float*)d_out;
  char* ws = (char*)d_ws;

  unsigned short* xb    = (unsigned short*)(ws + 0);          // [4096][2048]
  unsigned short* wqkvb = (unsigned short*)(ws + 16777216);   // [3072][2048]
  unsigned short* wob   = (unsigned short*)(ws + 29360128);   // [2048][2048]
  unsigned short* Qb    = (unsigned short*)(ws + 62914560);   // [2][32][2048][64]
  unsigned short* Kb    = (unsigned short*)(ws + 79691776);   // [2][8][2048][64]
  unsigned short* Vtb   = (unsigned short*)(ws + 83886080);   // [2][8][64][2048]
  unsigned short* attnb = (unsigned short*)(ws + 88080384);   // [4096][2048]

  k_cvt_all<<<18432, 256, 0, stream>>>(x, wq, wk, wv, wo, xb, wqkvb, wob);

  dim3 g1(24, 32);   // N=3072/128, M=4096/128 — fused RoPE/Vt epilogue
  k_gemm_qkv<<<g1, 256, 0, stream>>>(xb, wqkvb, fc, fs, Qb, Kb, Vtb);

  k_attn<<<512, 256, 0, stream>>>(Qb, Kb, Vtb, attnb);

  dim3 g2(16, 32);   // N=2048/128, M=4096/128
  k_gemm_bt<0><<<g2, 256, 0, stream>>>(attnb, wob, out, NROWS, DIMSZ, DIMSZ);
}